// Round 10
// baseline (1787.093 us; speedup 1.0000x reference)
//
#include <hip/hip_runtime.h>
#include <stdio.h>

// ---------------------------------------------------------------------------
// Projection (all fp32). One block per input row, 128 threads = one output
// column each. Y layout: [(bb*8+h)*L + l][16]  (head-major).
// ---------------------------------------------------------------------------
__global__ void proj_kernel(const float* X, const float* W, const float* bias,
                            float* Y, int L)
{
  int row = blockIdx.x;      // 0 .. 4*L-1
  int c   = threadIdx.x;     // 0 .. 127
  const float* xr = X + (size_t)row * 128;
  float acc = bias[c];
  for (int d = 0; d < 128; ++d)
    acc += xr[d] * W[d * 128 + c];
  int bb = row / L;
  int l  = row - bb * L;
  int h  = c >> 4;
  int dd = c & 15;
  Y[((size_t)(bb * 8 + h) * L + l) * 16 + dd] = acc;
}

// ---------------------------------------------------------------------------
// Attention pass (fp32). One wave per row. Scores x[j] in registers,
// k = lane + 64*j. entmax15 tau via guarded Newton on
// f(tau) = sum relu(x-tau)^2 - 1 from tau0 = -1 (f convex decreasing; after
// the max-shift f(-1) >= 0, so iterates converge monotonically from the left).
// Writes the full A row (fp32) and accumulates P@V into OutWs.
// ---------------------------------------------------------------------------
__global__ void attn_kernel(const float* RowM, const float* ColM,
                            const float* ValM, float* Aout, float* OutWs,
                            int Lrow, int Lcol)
{
  int wid  = blockIdx.x * 4 + (threadIdx.x >> 6);
  int lane = threadIdx.x & 63;
  int bh   = wid / Lrow;
  int row  = wid - bh * Lrow;
  int bb   = bh >> 3;
  int h    = bh & 7;
  int J    = Lcol >> 6;                            // 16 or 32

  float qf[16];
  const float* qp = RowM + ((size_t)bh * Lrow + row) * 16;
  for (int d = 0; d < 16; ++d) qf[d] = qp[d] * 0.125f;  // 1/sqrt(16) * 0.5

  float x[32];
  const float* Kb = ColM + (size_t)bh * Lcol * 16;
  for (int j = 0; j < J; ++j) {
    const float* kp = Kb + (size_t)(lane + 64 * j) * 16;
    float s = 0.f;
    for (int d = 0; d < 16; ++d) s += qf[d] * kp[d];
    x[j] = s;
  }

  float m = -1e30f;
  for (int j = 0; j < J; ++j) m = fmaxf(m, x[j]);
  for (int off = 32; off >= 1; off >>= 1) m = fmaxf(m, __shfl_xor(m, off));
  for (int j = 0; j < J; ++j) x[j] -= m;

  float tau = -1.0f;
  for (int it = 0; it < 40; ++it) {
    float s1 = 0.f, s2 = 0.f;
    for (int j = 0; j < J; ++j) {
      float t = fmaxf(x[j] - tau, 0.f);
      s1 += t;
      s2 += t * t;
    }
    for (int off = 32; off >= 1; off >>= 1) {
      s1 += __shfl_xor(s1, off);
      s2 += __shfl_xor(s2, off);
    }
    float f = s2 - 1.0f;
    if (!(f > 1e-7f) || !(s1 > 1e-12f)) break;   // wave-uniform
    tau += f / (2.0f * s1);
  }

  float acc[16];
  for (int d = 0; d < 16; ++d) acc[d] = 0.f;
  float* arow = Aout + ((size_t)bh * Lrow + row) * Lcol;
  const float* Vb = ValM + (size_t)bh * Lcol * 16;
  for (int j = 0; j < J; ++j) {
    int k = lane + 64 * j;
    float t = fmaxf(x[j] - tau, 0.f);
    float p = t * t;
    arow[k] = p;
    const float* vp = Vb + (size_t)k * 16;
    for (int d = 0; d < 16; ++d) acc[d] += p * vp[d];
  }
  for (int off = 32; off >= 1; off >>= 1)
    for (int d = 0; d < 16; ++d) acc[d] += __shfl_xor(acc[d], off);

  float v = acc[0];
  for (int d = 1; d < 16; ++d) v = (lane == d) ? acc[d] : v;
  if (lane < 16)
    OutWs[((size_t)bb * Lrow + row) * 128 + h * 16 + lane] = v;
}

// ---------------------------------------------------------------------------
// Y = X1 @ W1 + bias + X2 @ W2 (all fp32), separate output buffer.
// ---------------------------------------------------------------------------
__global__ void combine_kernel(const float* X1, const float* X2,
                               const float* W1, const float* W2,
                               const float* bias, float* Yo)
{
  int row = blockIdx.x;
  int c   = threadIdx.x;
  const float* x1 = X1 + (size_t)row * 128;
  const float* x2 = X2 + (size_t)row * 128;
  float acc = bias[c];
  for (int d = 0; d < 128; ++d)
    acc += x1[d] * W1[d * 128 + c] + x2[d] * W2[d * 128 + c];
  Yo[(size_t)row * 128 + c] = acc;
}

// ---------------------------------------------------------------------------
// LayerNorm + ReLU + fp32 store. One wave per row of 128 (block = 64).
// ---------------------------------------------------------------------------
__global__ void ln_kernel(const float* Y1, const float* Y2, const float* gamma,
                          const float* beta, float* O1, float* O2, int R1)
{
  int row  = blockIdx.x;
  int lane = threadIdx.x;   // 0..63
  const float* y = (row < R1) ? (Y1 + (size_t)row * 128)
                              : (Y2 + (size_t)(row - R1) * 128);
  float* o = (row < R1) ? (O1 + (size_t)row * 128)
                        : (O2 + (size_t)(row - R1) * 128);
  float a0 = y[lane];
  float a1 = y[lane + 64];
  float s  = a0 + a1;
  float s2 = a0 * a0 + a1 * a1;
  for (int off = 32; off >= 1; off >>= 1) {
    s  += __shfl_xor(s, off);
    s2 += __shfl_xor(s2, off);
  }
  float mu  = s * (1.f / 128.f);
  float var = fmaxf(s2 * (1.f / 128.f) - mu * mu, 0.f);
  float rs  = rsqrtf(var + 1e-5f);
  float o0 = fmaxf((a0 - mu) * rs * gamma[lane]      + beta[lane],      0.f);
  float o1 = fmaxf((a1 - mu) * rs * gamma[lane + 64] + beta[lane + 64], 0.f);
  o[lane]      = o0;
  o[lane + 64] = o1;
}

// ---------------------------------------------------------------------------
extern "C"
__attribute__((visibility("default"), used))
void kernel_launch(void* const* d_in, const int* in_sizes, int n_in,
                   void* d_out, int out_size, void* d_ws, size_t ws_size,
                   hipStream_t stream)
{
  (void)in_sizes; (void)n_in; (void)out_size; (void)ws_size;
  fprintf(stderr, "[kl] fp32 pipeline enter\n");
  fflush(stderr);

  const float* q     = (const float*)d_in[0];
  const float* k     = (const float*)d_in[1];
  const float* v     = (const float*)d_in[2];
  const float* v2    = (const float*)d_in[3];
  const float* W_Q   = (const float*)d_in[4];
  const float* b_Q   = (const float*)d_in[5];
  const float* W_K   = (const float*)d_in[6];
  const float* b_K   = (const float*)d_in[7];
  const float* W_V   = (const float*)d_in[8];
  const float* b_V   = (const float*)d_in[9];
  const float* W_V2  = (const float*)d_in[10];
  const float* b_V2  = (const float*)d_in[11];
  const float* W_O   = (const float*)d_in[12];
  const float* b_O   = (const float*)d_in[13];
  const float* W_O2  = (const float*)d_in[14];
  const float* b_O2  = (const float*)d_in[15];
  const float* W_R   = (const float*)d_in[16];
  const float* W_R2  = (const float*)d_in[17];
  const float* gamma = (const float*)d_in[18];
  const float* beta  = (const float*)d_in[19];

  char* ws = (char*)d_ws;
  const size_t MB = 1u << 20;
  float* Qp    = (float*)(ws + 0);        // [32][1024][16] f32 (2 MB)
  float* Kp    = (float*)(ws + 2 * MB);   // [32][2048][16] f32 (4 MB)
  float* Vp    = (float*)(ws + 6 * MB);   // [32][2048][16] f32 (4 MB)
  float* V2p   = (float*)(ws + 10 * MB);  // [32][1024][16] f32 (2 MB)
  float* outm1 = (float*)(ws + 12 * MB);  // attn out 1 (4096x128, 2 MB)
  float* outm2 = (float*)(ws + 14 * MB);  // attn out 2 (8192x128, 4 MB)
  float* outy1 = (float*)(ws + 18 * MB);  // combine out 1 (2 MB)
  float* outy2 = (float*)(ws + 20 * MB);  // combine out 2 (4 MB)

  float* out1  = (float*)d_out;              // (4,1024,128)
  float* out2  = out1 + (size_t)524288;      // (4,2048,128)
  float* Aout  = out1 + (size_t)1572864;     // (4,8,1024,2048)
  float* A2out = out1 + (size_t)68681728;    // (4,8,2048,1024)

  proj_kernel<<<4096, 128, 0, stream>>>(q,  W_Q,  b_Q,  Qp,  1024);
  proj_kernel<<<8192, 128, 0, stream>>>(k,  W_K,  b_K,  Kp,  2048);
  proj_kernel<<<8192, 128, 0, stream>>>(v,  W_V,  b_V,  Vp,  2048);
  proj_kernel<<<4096, 128, 0, stream>>>(v2, W_V2, b_V2, V2p, 1024);

  attn_kernel<<<8192,  256, 0, stream>>>(Qp, Kp, Vp,  Aout,  outm1, 1024, 2048);
  attn_kernel<<<16384, 256, 0, stream>>>(Kp, Qp, V2p, A2out, outm2, 2048, 1024);

  combine_kernel<<<4096, 128, 0, stream>>>(outm1, q, W_O,  W_R,  b_O,  outy1);
  combine_kernel<<<8192, 128, 0, stream>>>(outm2, k, W_O2, W_R2, b_O2, outy2);

  ln_kernel<<<12288, 64, 0, stream>>>(outy1, outy2, gamma, beta,
                                      out1, out2, 4096);
}

// Round 11
// 1395.186 us; speedup vs baseline: 1.2809x; 1.2809x over previous
//
#include <hip/hip_runtime.h>

// ---------------------------------------------------------------------------
// Projection (fp32). 4 rows per block, 128 threads = one output column each.
// X rows staged in LDS (broadcast reads). Y: [(bb*8+h)*L + l][16] head-major.
// ---------------------------------------------------------------------------
__global__ __launch_bounds__(128) void proj_kernel(
    const float* __restrict__ X, const float* __restrict__ W,
    const float* __restrict__ bias, float* __restrict__ Y, int L)
{
  __shared__ float xs[4][128];
  int rb = blockIdx.x * 4;
  int c  = threadIdx.x;            // 0..127
#pragma unroll
  for (int i = 0; i < 4; ++i)
    xs[i][c] = X[(size_t)(rb + i) * 128 + c];
  __syncthreads();
  float b = bias[c];
  float a0 = b, a1 = b, a2 = b, a3 = b;
#pragma unroll 8
  for (int d = 0; d < 128; ++d) {
    float w = W[d * 128 + c];
    a0 = fmaf(xs[0][d], w, a0);
    a1 = fmaf(xs[1][d], w, a1);
    a2 = fmaf(xs[2][d], w, a2);
    a3 = fmaf(xs[3][d], w, a3);
  }
  int h = c >> 4, dd = c & 15;
  float av[4] = { a0, a1, a2, a3 };
#pragma unroll
  for (int i = 0; i < 4; ++i) {
    int row = rb + i;
    int bb = row / L;
    int l  = row - bb * L;
    Y[((size_t)(bb * 8 + h) * L + l) * 16 + dd] = av[i];
  }
}

// ---------------------------------------------------------------------------
// Attention pass (fp32). One wave per 2 rows (shared K/V loads, 2x ILP).
// Scores x[j] in registers, k = lane + 64*j. entmax15 tau via guarded Newton
// on f(tau) = sum relu(x-tau)^2 - 1 from tau0 = -1 (f convex decreasing;
// after max-shift f(-1) >= 0 -> monotone convergence from the left).
// ---------------------------------------------------------------------------
template<int LROW, int LCOL>
__global__ __launch_bounds__(256) void attn_kernel(
    const float* __restrict__ RowM, const float* __restrict__ ColM,
    const float* __restrict__ ValM, float* __restrict__ Aout,
    float* __restrict__ OutWs)
{
  constexpr int J = LCOL / 64;
  int pid  = blockIdx.x * 4 + (threadIdx.x >> 6);   // row-pair id
  int lane = threadIdx.x & 63;
  int bh   = pid / (LROW / 2);
  int pr   = pid - bh * (LROW / 2);
  int row0 = pr * 2;
  int bb   = bh >> 3, h = bh & 7;

  float qf0[16], qf1[16];
  { const float* qp = RowM + ((size_t)bh * LROW + row0) * 16;
#pragma unroll
    for (int d = 0; d < 16; ++d) {
      qf0[d] = qp[d]      * 0.125f;   // 1/sqrt(16) * 0.5
      qf1[d] = qp[16 + d] * 0.125f;
    } }

  // -------- scores (both rows share each K load) --------
  float x0[J], x1[J];
  const float* Kb = ColM + (size_t)bh * LCOL * 16;
#pragma unroll
  for (int j = 0; j < J; ++j) {
    const float4* kp = (const float4*)(Kb + (size_t)(lane + 64 * j) * 16);
    float4 k0 = kp[0], k1 = kp[1], k2 = kp[2], k3 = kp[3];
    float kf[16] = { k0.x, k0.y, k0.z, k0.w, k1.x, k1.y, k1.z, k1.w,
                     k2.x, k2.y, k2.z, k2.w, k3.x, k3.y, k3.z, k3.w };
    float s0 = 0.f, s1 = 0.f;
#pragma unroll
    for (int d = 0; d < 16; ++d) {
      s0 = fmaf(qf0[d], kf[d], s0);
      s1 = fmaf(qf1[d], kf[d], s1);
    }
    x0[j] = s0; x1[j] = s1;
  }

  // -------- max-shift --------
  float m0 = -1e30f, m1 = -1e30f;
#pragma unroll
  for (int j = 0; j < J; ++j) { m0 = fmaxf(m0, x0[j]); m1 = fmaxf(m1, x1[j]); }
#pragma unroll
  for (int off = 32; off >= 1; off >>= 1) {
    m0 = fmaxf(m0, __shfl_xor(m0, off));
    m1 = fmaxf(m1, __shfl_xor(m1, off));
  }
#pragma unroll
  for (int j = 0; j < J; ++j) { x0[j] -= m0; x1[j] -= m1; }

  // -------- Newton for tau (both rows interleaved) --------
  float tau0 = -1.0f, tau1 = -1.0f;
  for (int it = 0; it < 40; ++it) {
    float a1 = 0.f, a2 = 0.f, b1 = 0.f, b2 = 0.f;
#pragma unroll
    for (int j = 0; j < J; ++j) {
      float t0 = fmaxf(x0[j] - tau0, 0.f); a1 += t0; a2 = fmaf(t0, t0, a2);
      float t1 = fmaxf(x1[j] - tau1, 0.f); b1 += t1; b2 = fmaf(t1, t1, b2);
    }
#pragma unroll
    for (int off = 32; off >= 1; off >>= 1) {
      a1 += __shfl_xor(a1, off); a2 += __shfl_xor(a2, off);
      b1 += __shfl_xor(b1, off); b2 += __shfl_xor(b2, off);
    }
    float f0 = a2 - 1.0f, f1 = b2 - 1.0f;
    bool c0 = (f0 > 1e-7f) && (a1 > 1e-12f);
    bool c1 = (f1 > 1e-7f) && (b1 > 1e-12f);
    if (!c0 && !c1) break;              // wave-uniform
    if (c0) tau0 += f0 / (2.0f * a1);
    if (c1) tau1 += f1 / (2.0f * b1);
  }

  // -------- A write + P@V (shared V loads) --------
  float acc0[16], acc1[16];
#pragma unroll
  for (int d = 0; d < 16; ++d) { acc0[d] = 0.f; acc1[d] = 0.f; }
  float* arow = Aout + ((size_t)bh * LROW + row0) * LCOL;
  const float* Vb = ValM + (size_t)bh * LCOL * 16;
#pragma unroll
  for (int j = 0; j < J; ++j) {
    int k = lane + 64 * j;
    float t0 = fmaxf(x0[j] - tau0, 0.f), p0 = t0 * t0;
    float t1 = fmaxf(x1[j] - tau1, 0.f), p1 = t1 * t1;
    arow[k]        = p0;
    arow[LCOL + k] = p1;
    const float4* vp = (const float4*)(Vb + (size_t)k * 16);
    float4 v0 = vp[0], v1 = vp[1], v2 = vp[2], v3 = vp[3];
    float vf[16] = { v0.x, v0.y, v0.z, v0.w, v1.x, v1.y, v1.z, v1.w,
                     v2.x, v2.y, v2.z, v2.w, v3.x, v3.y, v3.z, v3.w };
#pragma unroll
    for (int d = 0; d < 16; ++d) {
      acc0[d] = fmaf(p0, vf[d], acc0[d]);
      acc1[d] = fmaf(p1, vf[d], acc1[d]);
    }
  }
#pragma unroll
  for (int off = 32; off >= 1; off >>= 1)
#pragma unroll
    for (int d = 0; d < 16; ++d) {
      acc0[d] += __shfl_xor(acc0[d], off);
      acc1[d] += __shfl_xor(acc1[d], off);
    }
  float w0 = acc0[0], w1 = acc1[0];
#pragma unroll
  for (int d = 1; d < 16; ++d) {
    w0 = (lane == d) ? acc0[d] : w0;
    w1 = (lane == d) ? acc1[d] : w1;
  }
  float* op = OutWs + ((size_t)bb * LROW + row0) * 128 + h * 16;
  if (lane < 16) { op[lane] = w0; op[128 + lane] = w1; }
}

// ---------------------------------------------------------------------------
// Y = X1 @ W1 + bias + X2 @ W2 (fp32). 4 rows per block, LDS-staged X.
// ---------------------------------------------------------------------------
__global__ __launch_bounds__(128) void combine_kernel(
    const float* __restrict__ X1, const float* __restrict__ X2,
    const float* __restrict__ W1, const float* __restrict__ W2,
    const float* __restrict__ bias, float* __restrict__ Yo)
{
  __shared__ float x1s[4][128], x2s[4][128];
  int rb = blockIdx.x * 4;
  int c  = threadIdx.x;
#pragma unroll
  for (int i = 0; i < 4; ++i) {
    x1s[i][c] = X1[(size_t)(rb + i) * 128 + c];
    x2s[i][c] = X2[(size_t)(rb + i) * 128 + c];
  }
  __syncthreads();
  float b = bias[c];
  float a0 = b, a1 = b, a2 = b, a3 = b;
#pragma unroll 4
  for (int d = 0; d < 128; ++d) {
    float w1 = W1[d * 128 + c];
    float w2 = W2[d * 128 + c];
    a0 = fmaf(x1s[0][d], w1, fmaf(x2s[0][d], w2, a0));
    a1 = fmaf(x1s[1][d], w1, fmaf(x2s[1][d], w2, a1));
    a2 = fmaf(x1s[2][d], w1, fmaf(x2s[2][d], w2, a2));
    a3 = fmaf(x1s[3][d], w1, fmaf(x2s[3][d], w2, a3));
  }
  Yo[(size_t)(rb + 0) * 128 + c] = a0;
  Yo[(size_t)(rb + 1) * 128 + c] = a1;
  Yo[(size_t)(rb + 2) * 128 + c] = a2;
  Yo[(size_t)(rb + 3) * 128 + c] = a3;
}

// ---------------------------------------------------------------------------
// LayerNorm + ReLU. 4 rows per block (one wave each).
// ---------------------------------------------------------------------------
__global__ __launch_bounds__(256) void ln_kernel(
    const float* __restrict__ Y1, const float* __restrict__ Y2,
    const float* __restrict__ gamma, const float* __restrict__ beta,
    float* __restrict__ O1, float* __restrict__ O2, int R1)
{
  int row  = blockIdx.x * 4 + (threadIdx.x >> 6);
  int lane = threadIdx.x & 63;
  const float* y = (row < R1) ? (Y1 + (size_t)row * 128)
                              : (Y2 + (size_t)(row - R1) * 128);
  float* o = (row < R1) ? (O1 + (size_t)row * 128)
                        : (O2 + (size_t)(row - R1) * 128);
  float a0 = y[lane];
  float a1 = y[lane + 64];
  float s  = a0 + a1;
  float s2 = fmaf(a0, a0, a1 * a1);
#pragma unroll
  for (int off = 32; off >= 1; off >>= 1) {
    s  += __shfl_xor(s, off);
    s2 += __shfl_xor(s2, off);
  }
  float mu  = s * (1.f / 128.f);
  float var = fmaxf(s2 * (1.f / 128.f) - mu * mu, 0.f);
  float rs  = rsqrtf(var + 1e-5f);
  float o0 = fmaxf(fmaf((a0 - mu) * rs, gamma[lane],      beta[lane]),      0.f);
  float o1 = fmaxf(fmaf((a1 - mu) * rs, gamma[lane + 64], beta[lane + 64]), 0.f);
  o[lane]      = o0;
  o[lane + 64] = o1;
}

// ---------------------------------------------------------------------------
extern "C"
__attribute__((visibility("default"), used))
void kernel_launch(void* const* d_in, const int* in_sizes, int n_in,
                   void* d_out, int out_size, void* d_ws, size_t ws_size,
                   hipStream_t stream)
{
  (void)in_sizes; (void)n_in; (void)out_size; (void)ws_size;
  const float* q     = (const float*)d_in[0];
  const float* k     = (const float*)d_in[1];
  const float* v     = (const float*)d_in[2];
  const float* v2    = (const float*)d_in[3];
  const float* W_Q   = (const float*)d_in[4];
  const float* b_Q   = (const float*)d_in[5];
  const float* W_K   = (const float*)d_in[6];
  const float* b_K   = (const float*)d_in[7];
  const float* W_V   = (const float*)d_in[8];
  const float* b_V   = (const float*)d_in[9];
  const float* W_V2  = (const float*)d_in[10];
  const float* b_V2  = (const float*)d_in[11];
  const float* W_O   = (const float*)d_in[12];
  const float* b_O   = (const float*)d_in[13];
  const float* W_O2  = (const float*)d_in[14];
  const float* b_O2  = (const float*)d_in[15];
  const float* W_R   = (const float*)d_in[16];
  const float* W_R2  = (const float*)d_in[17];
  const float* gamma = (const float*)d_in[18];
  const float* beta  = (const float*)d_in[19];

  char* ws = (char*)d_ws;
  const size_t MB = 1u << 20;
  float* Qp    = (float*)(ws + 0);        // [32][1024][16] f32 (2 MB)
  float* Kp    = (float*)(ws + 2 * MB);   // [32][2048][16] f32 (4 MB)
  float* Vp    = (float*)(ws + 6 * MB);   // [32][2048][16] f32 (4 MB)
  float* V2p   = (float*)(ws + 10 * MB);  // [32][1024][16] f32 (2 MB)
  float* outm1 = (float*)(ws + 12 * MB);  // attn out 1 (4096x128, 2 MB)
  float* outm2 = (float*)(ws + 14 * MB);  // attn out 2 (8192x128, 4 MB)
  float* outy1 = (float*)(ws + 18 * MB);  // combine out 1 (2 MB)
  float* outy2 = (float*)(ws + 20 * MB);  // combine out 2 (4 MB)

  float* out1  = (float*)d_out;              // (4,1024,128)
  float* out2  = out1 + (size_t)524288;      // (4,2048,128)
  float* Aout  = out1 + (size_t)1572864;     // (4,8,1024,2048)
  float* A2out = out1 + (size_t)68681728;    // (4,8,2048,1024)

  proj_kernel<<<1024, 128, 0, stream>>>(q,  W_Q,  b_Q,  Qp,  1024);
  proj_kernel<<<2048, 128, 0, stream>>>(k,  W_K,  b_K,  Kp,  2048);
  proj_kernel<<<2048, 128, 0, stream>>>(v,  W_V,  b_V,  Vp,  2048);
  proj_kernel<<<1024, 128, 0, stream>>>(v2, W_V2, b_V2, V2p, 1024);

  attn_kernel<1024, 2048><<<4096, 256, 0, stream>>>(Qp, Kp, Vp,  Aout,  outm1);
  attn_kernel<2048, 1024><<<8192, 256, 0, stream>>>(Kp, Qp, V2p, A2out, outm2);

  combine_kernel<<<1024, 128, 0, stream>>>(outm1, q, W_O,  W_R,  b_O,  outy1);
  combine_kernel<<<2048, 128, 0, stream>>>(outm2, k, W_O2, W_R2, b_O2, outy2);

  ln_kernel<<<3072, 256, 0, stream>>>(outy1, outy2, gamma, beta,
                                      out1, out2, 4096);
}

// Round 12
// 1155.032 us; speedup vs baseline: 1.5472x; 1.2079x over previous
//
#include <hip/hip_runtime.h>

// ---------------------------------------------------------------------------
// Projection (fp32). 4 rows per block, 128 threads = one output column each.
// ---------------------------------------------------------------------------
__global__ __launch_bounds__(128) void proj_kernel(
    const float* __restrict__ X, const float* __restrict__ W,
    const float* __restrict__ bias, float* __restrict__ Y, int L)
{
  __shared__ float xs[4][128];
  int rb = blockIdx.x * 4;
  int c  = threadIdx.x;
#pragma unroll
  for (int i = 0; i < 4; ++i)
    xs[i][c] = X[(size_t)(rb + i) * 128 + c];
  __syncthreads();
  float b = bias[c];
  float a0 = b, a1 = b, a2 = b, a3 = b;
#pragma unroll 8
  for (int d = 0; d < 128; ++d) {
    float w = W[d * 128 + c];
    a0 = fmaf(xs[0][d], w, a0);
    a1 = fmaf(xs[1][d], w, a1);
    a2 = fmaf(xs[2][d], w, a2);
    a3 = fmaf(xs[3][d], w, a3);
  }
  int h = c >> 4, dd = c & 15;
  float av[4] = { a0, a1, a2, a3 };
#pragma unroll
  for (int i = 0; i < 4; ++i) {
    int row = rb + i;
    int bb = row / L;
    int l  = row - bb * L;
    Y[((size_t)(bb * 8 + h) * L + l) * 16 + dd] = av[i];
  }
}

// Guarded hybrid root step for f(u-shifted) = S2 - 1 over current support:
// exact segment root when discriminant real (never overshoots: assumed-support
// quadratic >= true f to the right), else Newton (tangent below convex f).
static __device__ __forceinline__ float hstep(float f, float s1, float cnt)
{
  float arg = fmaf(-cnt, f, s1 * s1);
  return (arg > 0.f) ? f / (s1 + sqrtf(arg)) : f / (2.f * s1);
}

// ---------------------------------------------------------------------------
// Attention pass (fp32). One wave per 2 rows. Scores in registers
// (k = lane + 64*j). entmax15 tau: monotone-from-left hybrid solver on raw
// scores with tau0 = max-1. Once support counts drop <= CAP, survivors are
// compacted (value+index) into per-wave LDS via wave prefix-sum; the
// remaining solver iterations, A-scatter and P@V touch only survivors.
// A is zero-filled with float4 stores, then sparse p's scattered.
// ---------------------------------------------------------------------------
template<int LROW, int LCOL>
__global__ __launch_bounds__(256) void attn_kernel(
    const float* __restrict__ RowM, const float* __restrict__ ColM,
    const float* __restrict__ ValM, float* __restrict__ Aout,
    float* __restrict__ OutWs)
{
  constexpr int J   = LCOL / 64;
  constexpr int CAP = 512;
  __shared__ float          sval[4][2][CAP];
  __shared__ unsigned short sidx[4][2][CAP];

  int ws   = threadIdx.x >> 6;                      // wave slot in block
  int pid  = blockIdx.x * 4 + ws;                   // row-pair id
  int lane = threadIdx.x & 63;
  int bh   = pid / (LROW / 2);
  int pr   = pid - bh * (LROW / 2);
  int row0 = pr * 2;
  int bb   = bh >> 3, h = bh & 7;

  float qf0[16], qf1[16];
  { const float* qp = RowM + ((size_t)bh * LROW + row0) * 16;
#pragma unroll
    for (int d = 0; d < 16; ++d) {
      qf0[d] = qp[d]      * 0.125f;                 // 1/sqrt(16) * 0.5
      qf1[d] = qp[16 + d] * 0.125f;
    } }

  // -------- scores (raw; max folded into tau0) --------
  float x0[J], x1[J];
  const float* Kb = ColM + (size_t)bh * LCOL * 16;
#pragma unroll
  for (int j = 0; j < J; ++j) {
    const float4* kp = (const float4*)(Kb + (size_t)(lane + 64 * j) * 16);
    float4 k0 = kp[0], k1 = kp[1], k2 = kp[2], k3 = kp[3];
    float kf[16] = { k0.x, k0.y, k0.z, k0.w, k1.x, k1.y, k1.z, k1.w,
                     k2.x, k2.y, k2.z, k2.w, k3.x, k3.y, k3.z, k3.w };
    float s0 = 0.f, s1 = 0.f;
#pragma unroll
    for (int d = 0; d < 16; ++d) {
      s0 = fmaf(qf0[d], kf[d], s0);
      s1 = fmaf(qf1[d], kf[d], s1);
    }
    x0[j] = s0; x1[j] = s1;
  }

  float m0 = -1e30f, m1 = -1e30f;
#pragma unroll
  for (int j = 0; j < J; ++j) { m0 = fmaxf(m0, x0[j]); m1 = fmaxf(m1, x1[j]); }
#pragma unroll
  for (int off = 32; off >= 1; off >>= 1) {
    m0 = fmaxf(m0, __shfl_xor(m0, off));
    m1 = fmaxf(m1, __shfl_xor(m1, off));
  }

  float tau0 = m0 - 1.0f, tau1 = m1 - 1.0f;

  // -------- full-register sweeps until converged or compactable --------
  bool done0 = false, done1 = false;
  bool compactable = false;
  for (int it = 0; it < 24; ++it) {
    float a1 = 0.f, a2 = 0.f, ac = 0.f;
    float b1 = 0.f, b2 = 0.f, bc = 0.f;
#pragma unroll
    for (int j = 0; j < J; ++j) {
      float t0 = x0[j] - tau0, r0 = fmaxf(t0, 0.f);
      a1 += r0; a2 = fmaf(r0, r0, a2); ac += (t0 > 0.f) ? 1.f : 0.f;
      float t1 = x1[j] - tau1, r1 = fmaxf(t1, 0.f);
      b1 += r1; b2 = fmaf(r1, r1, b2); bc += (t1 > 0.f) ? 1.f : 0.f;
    }
#pragma unroll
    for (int off = 32; off >= 1; off >>= 1) {
      a1 += __shfl_xor(a1, off); a2 += __shfl_xor(a2, off);
      ac += __shfl_xor(ac, off);
      b1 += __shfl_xor(b1, off); b2 += __shfl_xor(b2, off);
      bc += __shfl_xor(bc, off);
    }
    float f0 = a2 - 1.0f, f1 = b2 - 1.0f;
    bool g0 = !done0 && (f0 > 1e-6f) && (a1 > 1e-12f);
    bool g1 = !done1 && (f1 > 1e-6f) && (b1 > 1e-12f);
    if (g0) tau0 += hstep(f0, a1, ac); else done0 = true;
    if (g1) tau1 += hstep(f1, b1, bc); else done1 = true;
    if (ac <= (float)CAP && bc <= (float)CAP) { compactable = true; break; }
    if (done0 && done1) break;
  }

  float* arow = Aout + ((size_t)bh * LROW + row0) * LCOL;
  const float* Vb = ValM + (size_t)bh * LCOL * 16;
  float* op = OutWs + ((size_t)bb * LROW + row0) * 128 + h * 16;

  if (compactable) {
    // -------- compact survivors via wave prefix-sum --------
    int c0 = 0, c1 = 0;
#pragma unroll
    for (int j = 0; j < J; ++j) {
      c0 += (x0[j] > tau0) ? 1 : 0;
      c1 += (x1[j] > tau1) ? 1 : 0;
    }
    int i0 = c0, i1 = c1;
#pragma unroll
    for (int off = 1; off <= 32; off <<= 1) {
      int t0 = __shfl_up(i0, off);
      int t1 = __shfl_up(i1, off);
      if (lane >= off) { i0 += t0; i1 += t1; }
    }
    int base0 = i0 - c0, base1 = i1 - c1;
    int tot0 = __shfl(i0, 63), tot1 = __shfl(i1, 63);
    int w0 = 0, w1 = 0;
#pragma unroll
    for (int j = 0; j < J; ++j) {
      if (x0[j] > tau0) {
        sval[ws][0][base0 + w0] = x0[j];
        sidx[ws][0][base0 + w0] = (unsigned short)(lane + 64 * j);
        ++w0;
      }
      if (x1[j] > tau1) {
        sval[ws][1][base1 + w1] = x1[j];
        sidx[ws][1][base1 + w1] = (unsigned short)(lane + 64 * j);
        ++w1;
      }
    }
    __threadfence_block();   // wave-local LDS visibility across lanes

    // -------- compacted solver --------
    if (!(done0 && done1)) {
      for (int it = 0; it < 24; ++it) {
        float a1 = 0.f, a2 = 0.f, ac = 0.f;
        float b1 = 0.f, b2 = 0.f, bc = 0.f;
        for (int i = lane; i < tot0; i += 64) {
          float t = sval[ws][0][i] - tau0, r = fmaxf(t, 0.f);
          a1 += r; a2 = fmaf(r, r, a2); ac += (t > 0.f) ? 1.f : 0.f;
        }
        for (int i = lane; i < tot1; i += 64) {
          float t = sval[ws][1][i] - tau1, r = fmaxf(t, 0.f);
          b1 += r; b2 = fmaf(r, r, b2); bc += (t > 0.f) ? 1.f : 0.f;
        }
#pragma unroll
        for (int off = 32; off >= 1; off >>= 1) {
          a1 += __shfl_xor(a1, off); a2 += __shfl_xor(a2, off);
          ac += __shfl_xor(ac, off);
          b1 += __shfl_xor(b1, off); b2 += __shfl_xor(b2, off);
          bc += __shfl_xor(bc, off);
        }
        float f0 = a2 - 1.0f, f1 = b2 - 1.0f;
        bool g0 = !done0 && (f0 > 1e-6f) && (a1 > 1e-12f);
        bool g1 = !done1 && (f1 > 1e-6f) && (b1 > 1e-12f);
        if (g0) tau0 += hstep(f0, a1, ac); else done0 = true;
        if (g1) tau1 += hstep(f1, b1, bc); else done1 = true;
        if (done0 && done1) break;
      }
    }

    // -------- A zero-fill (wide) + sparse scatter + sparse P@V --------
    float4 z = { 0.f, 0.f, 0.f, 0.f };
    float4* a4_0 = (float4*)arow;
    float4* a4_1 = (float4*)(arow + LCOL);
#pragma unroll
    for (int i = lane; i < LCOL / 4; i += 64) { a4_0[i] = z; a4_1[i] = z; }
    __threadfence_block();   // order zero-fill before scatter (same wave)

    float acc0[16], acc1[16];
#pragma unroll
    for (int d = 0; d < 16; ++d) { acc0[d] = 0.f; acc1[d] = 0.f; }
    for (int i = lane; i < tot0; i += 64) {
      float t = sval[ws][0][i] - tau0;
      if (t > 0.f) {
        float p = t * t;
        int kk = sidx[ws][0][i];
        arow[kk] = p;
        const float4* vp = (const float4*)(Vb + (size_t)kk * 16);
        float4 v0 = vp[0], v1 = vp[1], v2 = vp[2], v3 = vp[3];
        float vf[16] = { v0.x, v0.y, v0.z, v0.w, v1.x, v1.y, v1.z, v1.w,
                         v2.x, v2.y, v2.z, v2.w, v3.x, v3.y, v3.z, v3.w };
#pragma unroll
        for (int d = 0; d < 16; ++d) acc0[d] = fmaf(p, vf[d], acc0[d]);
      }
    }
    for (int i = lane; i < tot1; i += 64) {
      float t = sval[ws][1][i] - tau1;
      if (t > 0.f) {
        float p = t * t;
        int kk = sidx[ws][1][i];
        arow[LCOL + kk] = p;
        const float4* vp = (const float4*)(Vb + (size_t)kk * 16);
        float4 v0 = vp[0], v1 = vp[1], v2 = vp[2], v3 = vp[3];
        float vf[16] = { v0.x, v0.y, v0.z, v0.w, v1.x, v1.y, v1.z, v1.w,
                         v2.x, v2.y, v2.z, v2.w, v3.x, v3.y, v3.z, v3.w };
#pragma unroll
        for (int d = 0; d < 16; ++d) acc1[d] = fmaf(p, vf[d], acc1[d]);
      }
    }
#pragma unroll
    for (int off = 32; off >= 1; off >>= 1)
#pragma unroll
      for (int d = 0; d < 16; ++d) {
        acc0[d] += __shfl_xor(acc0[d], off);
        acc1[d] += __shfl_xor(acc1[d], off);
      }
    float v0l = acc0[0], v1l = acc1[0];
#pragma unroll
    for (int d = 1; d < 16; ++d) {
      v0l = (lane == d) ? acc0[d] : v0l;
      v1l = (lane == d) ? acc1[d] : v1l;
    }
    if (lane < 16) { op[lane] = v0l; op[128 + lane] = v1l; }
    return;
  }

  // -------- fallback: dense A write + P@V (rare; large-support rows) --------
  float acc0[16], acc1[16];
#pragma unroll
  for (int d = 0; d < 16; ++d) { acc0[d] = 0.f; acc1[d] = 0.f; }
#pragma unroll
  for (int j = 0; j < J; ++j) {
    int kk = lane + 64 * j;
    float t0 = fmaxf(x0[j] - tau0, 0.f), p0 = t0 * t0;
    float t1 = fmaxf(x1[j] - tau1, 0.f), p1 = t1 * t1;
    arow[kk]        = p0;
    arow[LCOL + kk] = p1;
    const float4* vp = (const float4*)(Vb + (size_t)kk * 16);
    float4 v0 = vp[0], v1 = vp[1], v2 = vp[2], v3 = vp[3];
    float vf[16] = { v0.x, v0.y, v0.z, v0.w, v1.x, v1.y, v1.z, v1.w,
                     v2.x, v2.y, v2.z, v2.w, v3.x, v3.y, v3.z, v3.w };
#pragma unroll
    for (int d = 0; d < 16; ++d) {
      acc0[d] = fmaf(p0, vf[d], acc0[d]);
      acc1[d] = fmaf(p1, vf[d], acc1[d]);
    }
  }
#pragma unroll
  for (int off = 32; off >= 1; off >>= 1)
#pragma unroll
    for (int d = 0; d < 16; ++d) {
      acc0[d] += __shfl_xor(acc0[d], off);
      acc1[d] += __shfl_xor(acc1[d], off);
    }
  float w0 = acc0[0], w1 = acc1[0];
#pragma unroll
  for (int d = 1; d < 16; ++d) {
    w0 = (lane == d) ? acc0[d] : w0;
    w1 = (lane == d) ? acc1[d] : w1;
  }
  if (lane < 16) { op[lane] = w0; op[128 + lane] = w1; }
}

// ---------------------------------------------------------------------------
// Y = X1 @ W1 + bias + X2 @ W2 (fp32). 4 rows per block, LDS-staged X.
// ---------------------------------------------------------------------------
__global__ __launch_bounds__(128) void combine_kernel(
    const float* __restrict__ X1, const float* __restrict__ X2,
    const float* __restrict__ W1, const float* __restrict__ W2,
    const float* __restrict__ bias, float* __restrict__ Yo)
{
  __shared__ float x1s[4][128], x2s[4][128];
  int rb = blockIdx.x * 4;
  int c  = threadIdx.x;
#pragma unroll
  for (int i = 0; i < 4; ++i) {
    x1s[i][c] = X1[(size_t)(rb + i) * 128 + c];
    x2s[i][c] = X2[(size_t)(rb + i) * 128 + c];
  }
  __syncthreads();
  float b = bias[c];
  float a0 = b, a1 = b, a2 = b, a3 = b;
#pragma unroll 4
  for (int d = 0; d < 128; ++d) {
    float w1 = W1[d * 128 + c];
    float w2 = W2[d * 128 + c];
    a0 = fmaf(x1s[0][d], w1, fmaf(x2s[0][d], w2, a0));
    a1 = fmaf(x1s[1][d], w1, fmaf(x2s[1][d], w2, a1));
    a2 = fmaf(x1s[2][d], w1, fmaf(x2s[2][d], w2, a2));
    a3 = fmaf(x1s[3][d], w1, fmaf(x2s[3][d], w2, a3));
  }
  Yo[(size_t)(rb + 0) * 128 + c] = a0;
  Yo[(size_t)(rb + 1) * 128 + c] = a1;
  Yo[(size_t)(rb + 2) * 128 + c] = a2;
  Yo[(size_t)(rb + 3) * 128 + c] = a3;
}

// ---------------------------------------------------------------------------
// LayerNorm + ReLU. 4 rows per block (one wave each).
// ---------------------------------------------------------------------------
__global__ __launch_bounds__(256) void ln_kernel(
    const float* __restrict__ Y1, const float* __restrict__ Y2,
    const float* __restrict__ gamma, const float* __restrict__ beta,
    float* __restrict__ O1, float* __restrict__ O2, int R1)
{
  int row  = blockIdx.x * 4 + (threadIdx.x >> 6);
  int lane = threadIdx.x & 63;
  const float* y = (row < R1) ? (Y1 + (size_t)row * 128)
                              : (Y2 + (size_t)(row - R1) * 128);
  float* o = (row < R1) ? (O1 + (size_t)row * 128)
                        : (O2 + (size_t)(row - R1) * 128);
  float a0 = y[lane];
  float a1 = y[lane + 64];
  float s  = a0 + a1;
  float s2 = fmaf(a0, a0, a1 * a1);
#pragma unroll
  for (int off = 32; off >= 1; off >>= 1) {
    s  += __shfl_xor(s, off);
    s2 += __shfl_xor(s2, off);
  }
  float mu  = s * (1.f / 128.f);
  float var = fmaxf(s2 * (1.f / 128.f) - mu * mu, 0.f);
  float rs  = rsqrtf(var + 1e-5f);
  float o0 = fmaxf(fmaf((a0 - mu) * rs, gamma[lane],      beta[lane]),      0.f);
  float o1 = fmaxf(fmaf((a1 - mu) * rs, gamma[lane + 64], beta[lane + 64]), 0.f);
  o[lane]      = o0;
  o[lane + 64] = o1;
}

// ---------------------------------------------------------------------------
extern "C"
__attribute__((visibility("default"), used))
void kernel_launch(void* const* d_in, const int* in_sizes, int n_in,
                   void* d_out, int out_size, void* d_ws, size_t ws_size,
                   hipStream_t stream)
{
  (void)in_sizes; (void)n_in; (void)out_size; (void)ws_size;
  const float* q     = (const float*)d_in[0];
  const float* k     = (const float*)d_in[1];
  const float* v     = (const float*)d_in[2];
  const float* v2    = (const float*)d_in[3];
  const float* W_Q   = (const float*)d_in[4];
  const float* b_Q   = (const float*)d_in[5];
  const float* W_K   = (const float*)d_in[6];
  const float* b_K   = (const float*)d_in[7];
  const float* W_V   = (const float*)d_in[8];
  const float* b_V   = (const float*)d_in[9];
  const float* W_V2  = (const float*)d_in[10];
  const float* b_V2  = (const float*)d_in[11];
  const float* W_O   = (const float*)d_in[12];
  const float* b_O   = (const float*)d_in[13];
  const float* W_O2  = (const float*)d_in[14];
  const float* b_O2  = (const float*)d_in[15];
  const float* W_R   = (const float*)d_in[16];
  const float* W_R2  = (const float*)d_in[17];
  const float* gamma = (const float*)d_in[18];
  const float* beta  = (const float*)d_in[19];

  char* ws = (char*)d_ws;
  const size_t MB = 1u << 20;
  float* Qp    = (float*)(ws + 0);
  float* Kp    = (float*)(ws + 2 * MB);
  float* Vp    = (float*)(ws + 6 * MB);
  float* V2p   = (float*)(ws + 10 * MB);
  float* outm1 = (float*)(ws + 12 * MB);
  float* outm2 = (float*)(ws + 14 * MB);
  float* outy1 = (float*)(ws + 18 * MB);
  float* outy2 = (float*)(ws + 20 * MB);

  float* out1  = (float*)d_out;              // (4,1024,128)
  float* out2  = out1 + (size_t)524288;      // (4,2048,128)
  float* Aout  = out1 + (size_t)1572864;     // (4,8,1024,2048)
  float* A2out = out1 + (size_t)68681728;    // (4,8,2048,1024)

  proj_kernel<<<1024, 128, 0, stream>>>(q,  W_Q,  b_Q,  Qp,  1024);
  proj_kernel<<<2048, 128, 0, stream>>>(k,  W_K,  b_K,  Kp,  2048);
  proj_kernel<<<2048, 128, 0, stream>>>(v,  W_V,  b_V,  Vp,  2048);
  proj_kernel<<<1024, 128, 0, stream>>>(v2, W_V2, b_V2, V2p, 1024);

  attn_kernel<1024, 2048><<<4096, 256, 0, stream>>>(Qp, Kp, Vp,  Aout,  outm1);
  attn_kernel<2048, 1024><<<8192, 256, 0, stream>>>(Kp, Qp, V2p, A2out, outm2);

  combine_kernel<<<1024, 128, 0, stream>>>(outm1, q, W_O,  W_R,  b_O,  outy1);
  combine_kernel<<<2048, 128, 0, stream>>>(outm2, k, W_O2, W_R2, b_O2, outy2);

  ln_kernel<<<3072, 256, 0, stream>>>(outy1, outy2, gamma, beta,
                                      out1, out2, 4096);
}